// Round 5
// baseline (38.072 us; speedup 1.0000x reference)
//
#include <hip/hip_runtime.h>

#define IGNORE_LABEL 255
#define MIN_KEPT 100000u
#define THRESH 0.7f
#define LOG_THRESH (-0.3566749439387324f)   // ln(0.7)

constexpr int N_PIX = 1 << 21;                 // 2*16*256*256 pixels (b,d,h,w)
constexpr int C = 16;                          // channels
constexpr int CH_STRIDE = 1 << 20;             // d*h*w
constexpr int B_STRIDE = C * CH_STRIDE;
constexpr int NBLK = 4096;                     // 4096 blk * 256 thr * 2 pix = N_PIX

typedef float f32x2 __attribute__((ext_vector_type(2)));

// ---------------------------------------------------------------------------
// Fused pass: per-pixel log-softmax; speculative OHEM sums assuming the
// threshold is exactly 0.7 (true iff count >= MIN_KEPT, checked in k_final).
// Log-domain: p_target <= 0.7  <=>  u = (x_t - m) - lse <= ln(0.7); nll = -u.
// 2 pixels/thread keeps the live channel array at 32 VGPRs so >=6 waves/SIMD
// stay resident to hide HBM latency on the 16-stream strided read.
// ---------------------------------------------------------------------------
__global__ __launch_bounds__(256, 6) void k_fused(const float* __restrict__ pred,
                                                  const int* __restrict__ target,
                                                  float* __restrict__ psum,
                                                  float* __restrict__ pcnt) {
    int tid = blockIdx.x * 256 + threadIdx.x;
    int n = tid * 2;                           // 2 consecutive pixels
    int b = n >> 20;
    int rem = n & (CH_STRIDE - 1);
    const float* base = pred + b * B_STRIDE + rem;

    int2 tg2 = *reinterpret_cast<const int2*>(target + n);
    int tgv[2] = {tg2.x, tg2.y};

    f32x2 x[C];
#pragma unroll
    for (int c = 0; c < C; ++c)
        x[c] = *reinterpret_cast<const f32x2*>(base + c * CH_STRIDE);

    float s = 0.0f, cn = 0.0f;
#pragma unroll
    for (int j = 0; j < 2; ++j) {
        int t = tgv[j];
        bool valid = (t != IGNORE_LABEL);
        int t0 = valid ? t : 0;

        float m = fmaxf(fmaxf(fmaxf(x[0][j], x[1][j]), fmaxf(x[2][j], x[3][j])),
                        fmaxf(fmaxf(x[4][j], x[5][j]), fmaxf(x[6][j], x[7][j])));
        float m2 = fmaxf(fmaxf(fmaxf(x[8][j], x[9][j]), fmaxf(x[10][j], x[11][j])),
                         fmaxf(fmaxf(x[12][j], x[13][j]), fmaxf(x[14][j], x[15][j])));
        m = fmaxf(m, m2);

        float se = 0.0f;
        float xt = x[0][j];
#pragma unroll
        for (int c = 0; c < C; ++c) {
            se += __expf(x[c][j] - m);
            if (c == t0) xt = x[c][j];         // compile-time c vs runtime t0 -> cndmask
        }
        float u = (xt - m) - __logf(se);       // log p_target
        bool keep = valid && (u <= LOG_THRESH);
        float k = keep ? 1.0f : 0.0f;
        s += k * (-u);                          // nll = -log p
        cn += k;
    }

    // wave + block reduce (deterministic order)
#pragma unroll
    for (int off = 32; off > 0; off >>= 1) {
        s += __shfl_down(s, off);
        cn += __shfl_down(cn, off);
    }
    __shared__ float ls[4], lc[4];
    int lane = threadIdx.x & 63, w = threadIdx.x >> 6;
    if (lane == 0) { ls[w] = s; lc[w] = cn; }
    __syncthreads();
    if (threadIdx.x == 0) {
        psum[blockIdx.x] = ls[0] + ls[1] + ls[2] + ls[3];
        pcnt[blockIdx.x] = lc[0] + lc[1] + lc[2] + lc[3];
    }
}

// Scalar recompute of masked target-prob + nll for one pixel (slow path only).
__device__ __noinline__ float slow_prob(const float* __restrict__ pred,
                                        const int* __restrict__ target,
                                        int n, float* nll) {
    int b = n >> 20, rem = n & (CH_STRIDE - 1);
    const float* base = pred + b * B_STRIDE + rem;
    int t = target[n];
    bool valid = (t != IGNORE_LABEL);
    int t0 = valid ? t : 0;
    float xs[C], m = -1e30f;
#pragma unroll
    for (int c = 0; c < C; ++c) { xs[c] = base[c * CH_STRIDE]; m = fmaxf(m, xs[c]); }
    float se = 0.0f, xt = xs[0];
#pragma unroll
    for (int c = 0; c < C; ++c) {
        se += __expf(xs[c] - m);
        if (c == t0) xt = xs[c];
    }
    float d = xt - m;
    *nll = __logf(se) - d;
    float p = __expf(d) / se;
    return valid ? p : 1.0f;
}

// ---------------------------------------------------------------------------
// Final: combine partials. Fast path (cnt >= MIN_KEPT): threshold is exactly
// 0.7, speculative sums are the answer. Slow path (never taken for this
// input, kept for correctness): exact 3-level radix select over recomputed
// mask_prob bit patterns, then masked mean.
// ---------------------------------------------------------------------------
__global__ __launch_bounds__(256) void k_final(const float* __restrict__ psum,
                                               const float* __restrict__ pcnt,
                                               const float* __restrict__ pred,
                                               const int* __restrict__ target,
                                               float* __restrict__ out) {
    int tid = threadIdx.x;
    __shared__ double rs[256], rc[256];
    double s = 0.0, c = 0.0;
    for (int i = tid; i < NBLK; i += 256) { s += (double)psum[i]; c += (double)pcnt[i]; }
    rs[tid] = s; rc[tid] = c;
    __syncthreads();
    for (int off = 128; off > 0; off >>= 1) {
        if (tid < off) { rs[tid] += rs[tid + off]; rc[tid] += rc[tid + off]; }
        __syncthreads();
    }
    double tots = rs[0], totc = rc[0];        // uniform across block after sync

    if (totc >= (double)MIN_KEPT) {
        if (tid == 0) out[0] = (float)(tots / (totc < 1.0 ? 1.0 : totc));
        return;                                // uniform exit
    }

    // ---- slow exact path ----
    __shared__ unsigned h[4096];
    __shared__ unsigned s_bin, s_krem;
    float dummy;

    // level 0: bits >> 20
    for (int i = tid; i < 4096; i += 256) h[i] = 0;
    __syncthreads();
    for (int nn = tid; nn < N_PIX; nn += 256) {
        unsigned bits = __float_as_uint(slow_prob(pred, target, nn, &dummy));
        atomicAdd(&h[bits >> 20], 1u);
    }
    __syncthreads();
    if (tid == 0) {
        unsigned run = 0;
        for (unsigned bb = 0; bb < 4096; ++bb) {
            unsigned cv = h[bb];
            if (MIN_KEPT <= run + cv) { s_bin = bb; s_krem = MIN_KEPT - run; break; }
            run += cv;
        }
    }
    __syncthreads();
    unsigned p0 = s_bin, k1 = s_krem;
    __syncthreads();

    // level 1: (bits >> 8) & 0xFFF
    for (int i = tid; i < 4096; i += 256) h[i] = 0;
    __syncthreads();
    for (int nn = tid; nn < N_PIX; nn += 256) {
        unsigned bits = __float_as_uint(slow_prob(pred, target, nn, &dummy));
        if ((bits >> 20) == p0) atomicAdd(&h[(bits >> 8) & 0xFFFu], 1u);
    }
    __syncthreads();
    if (tid == 0) {
        unsigned run = 0;
        for (unsigned bb = 0; bb < 4096; ++bb) {
            unsigned cv = h[bb];
            if (k1 <= run + cv) { s_bin = bb; s_krem = k1 - run; break; }
            run += cv;
        }
    }
    __syncthreads();
    unsigned p1 = (p0 << 12) | s_bin;
    unsigned k2 = s_krem;
    __syncthreads();

    // level 2: bits & 0xFF
    for (int i = tid; i < 256; i += 256) h[i] = 0;
    __syncthreads();
    for (int nn = tid; nn < N_PIX; nn += 256) {
        unsigned bits = __float_as_uint(slow_prob(pred, target, nn, &dummy));
        if ((bits >> 8) == p1) atomicAdd(&h[bits & 0xFFu], 1u);
    }
    __syncthreads();
    if (tid == 0) {
        unsigned run = 0;
        for (unsigned bb = 0; bb < 256; ++bb) {
            unsigned cv = h[bb];
            if (k2 <= run + cv) { s_bin = (p1 << 8) | bb; break; }
            run += cv;
        }
    }
    __syncthreads();
    float thr = fmaxf(THRESH, __uint_as_float(s_bin));

    // masked mean at exact threshold
    double fs = 0.0, fc = 0.0;
    for (int nn = tid; nn < N_PIX; nn += 256) {
        float nll;
        float mp = slow_prob(pred, target, nn, &nll);
        if (target[nn] != IGNORE_LABEL && mp <= thr) { fs += (double)nll; fc += 1.0; }
    }
    __syncthreads();
    rs[tid] = fs; rc[tid] = fc;
    __syncthreads();
    for (int off = 128; off > 0; off >>= 1) {
        if (tid < off) { rs[tid] += rs[tid + off]; rc[tid] += rc[tid + off]; }
        __syncthreads();
    }
    if (tid == 0) {
        double cc = rc[0] < 1.0 ? 1.0 : rc[0];
        out[0] = (float)(rs[0] / cc);
    }
}

extern "C" void kernel_launch(void* const* d_in, const int* in_sizes, int n_in,
                              void* d_out, int out_size, void* d_ws, size_t ws_size,
                              hipStream_t stream) {
    const float* pred = (const float*)d_in[0];
    const int* target = (const int*)d_in[1];
    float* out = (float*)d_out;

    float* psum = (float*)d_ws;                // NBLK floats, written before read
    float* pcnt = psum + NBLK;                 // NBLK floats

    k_fused<<<NBLK, 256, 0, stream>>>(pred, target, psum, pcnt);
    k_final<<<1, 256, 0, stream>>>(psum, pcnt, pred, target, out);
}

// Round 6
// 32.602 us; speedup vs baseline: 1.1678x; 1.1678x over previous
//
#include <hip/hip_runtime.h>

#define IGNORE_LABEL 255
#define MIN_KEPT 100000u
#define THRESH 0.7f
#define LOG_THRESH (-0.3566749439387324f)   // ln(0.7)

constexpr int N_PIX = 1 << 21;                 // 2*16*256*256 pixels (b,d,h,w)
constexpr int C = 16;                          // channels
constexpr int CH_STRIDE = 1 << 20;             // d*h*w
constexpr int B_STRIDE = C * CH_STRIDE;
constexpr int NBLK = 2048;                     // 2048 blk * 256 thr * 4 px = N_PIX

typedef float f32x4 __attribute__((ext_vector_type(4)));

// ---------------------------------------------------------------------------
// Fused pass: ONLINE per-pixel log-softmax over the 16 strided channel
// streams. Running (m, se, xt) state per pixel means compute interleaves
// with load returns (no all-16 vmcnt drain), live VGPRs stay ~40 (8
// waves/SIMD), and all 16 channel loads stay in flight per wave.
// Speculative OHEM sums assume threshold==0.7 (true iff count >= MIN_KEPT,
// verified in k_final; exact slow path there otherwise).
// ---------------------------------------------------------------------------
__global__ __launch_bounds__(256) void k_fused(const float* __restrict__ pred,
                                               const int* __restrict__ target,
                                               float2* __restrict__ part) {
    int tid = blockIdx.x * 256 + threadIdx.x;
    int n = tid * 4;                           // 4 consecutive pixels
    int b = n >> 20;
    int rem = n & (CH_STRIDE - 1);
    const float* base = pred + b * B_STRIDE + rem;

    int4 tg4 = *reinterpret_cast<const int4*>(target + n);
    int t0v[4]; float validf[4];
    {
        int tgv[4] = {tg4.x, tg4.y, tg4.z, tg4.w};
#pragma unroll
        for (int j = 0; j < 4; ++j) {
            bool valid = (tgv[j] != IGNORE_LABEL);
            t0v[j] = valid ? tgv[j] : 0;
            validf[j] = valid ? 1.0f : 0.0f;
        }
    }

    // init from channel 0
    f32x4 v0 = *reinterpret_cast<const f32x4*>(base);
    float m[4], se[4], xt[4];
#pragma unroll
    for (int j = 0; j < 4; ++j) { m[j] = v0[j]; se[j] = 1.0f; xt[j] = v0[j]; }

#pragma unroll
    for (int c = 1; c < C; ++c) {
        f32x4 v = *reinterpret_cast<const f32x4*>(base + c * CH_STRIDE);
#pragma unroll
        for (int j = 0; j < 4; ++j) {
            float x = v[j];
            float mN = fmaxf(m[j], x);
            se[j] = se[j] * __expf(m[j] - mN) + __expf(x - mN);
            m[j] = mN;
            xt[j] = (c == t0v[j]) ? x : xt[j];   // compile-time c -> cndmask
        }
    }

    float s = 0.0f, cn = 0.0f;
#pragma unroll
    for (int j = 0; j < 4; ++j) {
        float u = (xt[j] - m[j]) - __logf(se[j]);   // log p_target
        bool keep = (validf[j] != 0.0f) && (u <= LOG_THRESH);
        float k = keep ? 1.0f : 0.0f;
        s += k * (-u);                              // nll = -log p
        cn += k;
    }

    // wave + block reduce (deterministic order)
#pragma unroll
    for (int off = 32; off > 0; off >>= 1) {
        s += __shfl_down(s, off);
        cn += __shfl_down(cn, off);
    }
    __shared__ float ls[4], lc[4];
    int lane = threadIdx.x & 63, w = threadIdx.x >> 6;
    if (lane == 0) { ls[w] = s; lc[w] = cn; }
    __syncthreads();
    if (threadIdx.x == 0) {
        float2 o;
        o.x = ls[0] + ls[1] + ls[2] + ls[3];
        o.y = lc[0] + lc[1] + lc[2] + lc[3];
        part[blockIdx.x] = o;
    }
}

// Scalar recompute of masked target-prob + nll for one pixel (slow path only).
__device__ __noinline__ float slow_prob(const float* __restrict__ pred,
                                        const int* __restrict__ target,
                                        int n, float* nll) {
    int b = n >> 20, rem = n & (CH_STRIDE - 1);
    const float* base = pred + b * B_STRIDE + rem;
    int t = target[n];
    bool valid = (t != IGNORE_LABEL);
    int t0 = valid ? t : 0;
    float xs[C], m = -1e30f;
#pragma unroll
    for (int c = 0; c < C; ++c) { xs[c] = base[c * CH_STRIDE]; m = fmaxf(m, xs[c]); }
    float se = 0.0f, xt = xs[0];
#pragma unroll
    for (int c = 0; c < C; ++c) {
        se += __expf(xs[c] - m);
        if (c == t0) xt = xs[c];
    }
    float d = xt - m;
    *nll = __logf(se) - d;
    float p = __expf(d) / se;
    return valid ? p : 1.0f;
}

// ---------------------------------------------------------------------------
// Final: combine partials. Fast path (cnt >= MIN_KEPT): threshold is exactly
// 0.7, speculative sums are the answer. Slow path (never taken for this
// input, kept for correctness): exact 3-level radix select over recomputed
// mask_prob bit patterns, then masked mean.
// ---------------------------------------------------------------------------
__global__ __launch_bounds__(256) void k_final(const float2* __restrict__ part,
                                               const float* __restrict__ pred,
                                               const int* __restrict__ target,
                                               float* __restrict__ out) {
    int tid = threadIdx.x;
    __shared__ double rs[256], rc[256];
    double s = 0.0, c = 0.0;
    for (int i = tid; i < NBLK; i += 256) {
        float2 p = part[i];
        s += (double)p.x; c += (double)p.y;
    }
    rs[tid] = s; rc[tid] = c;
    __syncthreads();
    for (int off = 128; off > 0; off >>= 1) {
        if (tid < off) { rs[tid] += rs[tid + off]; rc[tid] += rc[tid + off]; }
        __syncthreads();
    }
    double tots = rs[0], totc = rc[0];        // uniform across block after sync

    if (totc >= (double)MIN_KEPT) {
        if (tid == 0) out[0] = (float)(tots / (totc < 1.0 ? 1.0 : totc));
        return;                                // uniform exit
    }

    // ---- slow exact path ----
    __shared__ unsigned h[4096];
    __shared__ unsigned s_bin, s_krem;
    float dummy;

    // level 0: bits >> 20
    for (int i = tid; i < 4096; i += 256) h[i] = 0;
    __syncthreads();
    for (int nn = tid; nn < N_PIX; nn += 256) {
        unsigned bits = __float_as_uint(slow_prob(pred, target, nn, &dummy));
        atomicAdd(&h[bits >> 20], 1u);
    }
    __syncthreads();
    if (tid == 0) {
        unsigned run = 0;
        for (unsigned bb = 0; bb < 4096; ++bb) {
            unsigned cv = h[bb];
            if (MIN_KEPT <= run + cv) { s_bin = bb; s_krem = MIN_KEPT - run; break; }
            run += cv;
        }
    }
    __syncthreads();
    unsigned p0 = s_bin, k1 = s_krem;
    __syncthreads();

    // level 1: (bits >> 8) & 0xFFF
    for (int i = tid; i < 4096; i += 256) h[i] = 0;
    __syncthreads();
    for (int nn = tid; nn < N_PIX; nn += 256) {
        unsigned bits = __float_as_uint(slow_prob(pred, target, nn, &dummy));
        if ((bits >> 20) == p0) atomicAdd(&h[(bits >> 8) & 0xFFFu], 1u);
    }
    __syncthreads();
    if (tid == 0) {
        unsigned run = 0;
        for (unsigned bb = 0; bb < 4096; ++bb) {
            unsigned cv = h[bb];
            if (k1 <= run + cv) { s_bin = bb; s_krem = k1 - run; break; }
            run += cv;
        }
    }
    __syncthreads();
    unsigned p1 = (p0 << 12) | s_bin;
    unsigned k2 = s_krem;
    __syncthreads();

    // level 2: bits & 0xFF
    for (int i = tid; i < 256; i += 256) h[i] = 0;
    __syncthreads();
    for (int nn = tid; nn < N_PIX; nn += 256) {
        unsigned bits = __float_as_uint(slow_prob(pred, target, nn, &dummy));
        if ((bits >> 8) == p1) atomicAdd(&h[bits & 0xFFu], 1u);
    }
    __syncthreads();
    if (tid == 0) {
        unsigned run = 0;
        for (unsigned bb = 0; bb < 256; ++bb) {
            unsigned cv = h[bb];
            if (k2 <= run + cv) { s_bin = (p1 << 8) | bb; break; }
            run += cv;
        }
    }
    __syncthreads();
    float thr = fmaxf(THRESH, __uint_as_float(s_bin));

    // masked mean at exact threshold
    double fs = 0.0, fc = 0.0;
    for (int nn = tid; nn < N_PIX; nn += 256) {
        float nll;
        float mp = slow_prob(pred, target, nn, &nll);
        if (target[nn] != IGNORE_LABEL && mp <= thr) { fs += (double)nll; fc += 1.0; }
    }
    __syncthreads();
    rs[tid] = fs; rc[tid] = fc;
    __syncthreads();
    for (int off = 128; off > 0; off >>= 1) {
        if (tid < off) { rs[tid] += rs[tid + off]; rc[tid] += rc[tid + off]; }
        __syncthreads();
    }
    if (tid == 0) {
        double cc = rc[0] < 1.0 ? 1.0 : rc[0];
        out[0] = (float)(rs[0] / cc);
    }
}

extern "C" void kernel_launch(void* const* d_in, const int* in_sizes, int n_in,
                              void* d_out, int out_size, void* d_ws, size_t ws_size,
                              hipStream_t stream) {
    const float* pred = (const float*)d_in[0];
    const int* target = (const int*)d_in[1];
    float* out = (float*)d_out;

    float2* part = (float2*)d_ws;              // NBLK float2, written before read

    k_fused<<<NBLK, 256, 0, stream>>>(pred, target, part);
    k_final<<<1, 256, 0, stream>>>(part, pred, target, out);
}

// Round 7
// 31.539 us; speedup vs baseline: 1.2071x; 1.0337x over previous
//
#include <hip/hip_runtime.h>

#define IGNORE_LABEL 255
#define MIN_KEPT 100000u
#define THRESH 0.7f
#define LOG_THRESH (-0.3566749439387324f)   // ln(0.7)

constexpr int N_PIX = 1 << 21;                 // 2*16*256*256 pixels (b,d,h,w)
constexpr int C = 16;                          // channels
constexpr int CH_STRIDE = 1 << 20;             // d*h*w
constexpr int B_STRIDE = C * CH_STRIDE;
constexpr int NBLK = 2048;                     // 2048 blk * 256 thr * 4 px = N_PIX

typedef float f32x4 __attribute__((ext_vector_type(4)));

// ---------------------------------------------------------------------------
// Fused pass: ONLINE per-pixel log-softmax over the 16 strided channel
// streams; compute interleaves with load returns (no all-16 vmcnt drain).
// Single-exp online update: with mN = max(m,x) and t = exp(-|x-m|),
//   x<=m:  se' = se + t          (t = exp(x-m))
//   x> m:  se' = fma(se, t, 1)   (t = exp(m-x))
// -> exactly the same values as the 2-exp form at half the trans-pipe cost.
// Speculative OHEM sums assume threshold==0.7 (true iff count >= MIN_KEPT,
// verified in k_final; exact slow path there otherwise).
// ---------------------------------------------------------------------------
__global__ __launch_bounds__(256) void k_fused(const float* __restrict__ pred,
                                               const int* __restrict__ target,
                                               float2* __restrict__ part) {
    int tid = blockIdx.x * 256 + threadIdx.x;
    int n = tid * 4;                           // 4 consecutive pixels
    int b = n >> 20;
    int rem = n & (CH_STRIDE - 1);
    const float* base = pred + b * B_STRIDE + rem;

    int4 tg4 = *reinterpret_cast<const int4*>(target + n);
    int t0v[4]; float validf[4];
    {
        int tgv[4] = {tg4.x, tg4.y, tg4.z, tg4.w};
#pragma unroll
        for (int j = 0; j < 4; ++j) {
            bool valid = (tgv[j] != IGNORE_LABEL);
            t0v[j] = valid ? tgv[j] : 0;
            validf[j] = valid ? 1.0f : 0.0f;
        }
    }

    // init from channel 0
    f32x4 v0 = *reinterpret_cast<const f32x4*>(base);
    float m[4], se[4], xt[4];
#pragma unroll
    for (int j = 0; j < 4; ++j) { m[j] = v0[j]; se[j] = 1.0f; xt[j] = v0[j]; }

#pragma unroll
    for (int c = 1; c < C; ++c) {
        f32x4 v = *reinterpret_cast<const f32x4*>(base + c * CH_STRIDE);
#pragma unroll
        for (int j = 0; j < 4; ++j) {
            float x = v[j];
            float t = __expf(-fabsf(x - m[j]));     // one exp serves both cases
            bool gt = x > m[j];
            float s1 = gt ? t : 1.0f;
            float s2 = gt ? 1.0f : t;
            se[j] = fmaf(se[j], s1, s2);
            m[j] = fmaxf(m[j], x);
            xt[j] = (c == t0v[j]) ? x : xt[j];      // compile-time c -> cndmask
        }
    }

    float s = 0.0f, cn = 0.0f;
#pragma unroll
    for (int j = 0; j < 4; ++j) {
        float u = (xt[j] - m[j]) - __logf(se[j]);   // log p_target
        bool keep = (validf[j] != 0.0f) && (u <= LOG_THRESH);
        float k = keep ? 1.0f : 0.0f;
        s += k * (-u);                              // nll = -log p
        cn += k;
    }

    // wave + block reduce (deterministic order)
#pragma unroll
    for (int off = 32; off > 0; off >>= 1) {
        s += __shfl_down(s, off);
        cn += __shfl_down(cn, off);
    }
    __shared__ float ls[4], lc[4];
    int lane = threadIdx.x & 63, w = threadIdx.x >> 6;
    if (lane == 0) { ls[w] = s; lc[w] = cn; }
    __syncthreads();
    if (threadIdx.x == 0) {
        float2 o;
        o.x = ls[0] + ls[1] + ls[2] + ls[3];
        o.y = lc[0] + lc[1] + lc[2] + lc[3];
        part[blockIdx.x] = o;
    }
}

// Scalar recompute of masked target-prob + nll for one pixel (slow path only).
__device__ __noinline__ float slow_prob(const float* __restrict__ pred,
                                        const int* __restrict__ target,
                                        int n, float* nll) {
    int b = n >> 20, rem = n & (CH_STRIDE - 1);
    const float* base = pred + b * B_STRIDE + rem;
    int t = target[n];
    bool valid = (t != IGNORE_LABEL);
    int t0 = valid ? t : 0;
    float xs[C], m = -1e30f;
#pragma unroll
    for (int c = 0; c < C; ++c) { xs[c] = base[c * CH_STRIDE]; m = fmaxf(m, xs[c]); }
    float se = 0.0f, xt = xs[0];
#pragma unroll
    for (int c = 0; c < C; ++c) {
        se += __expf(xs[c] - m);
        if (c == t0) xt = xs[c];
    }
    float d = xt - m;
    *nll = __logf(se) - d;
    float p = __expf(d) / se;
    return valid ? p : 1.0f;
}

// ---------------------------------------------------------------------------
// Final: combine partials. Fast path (cnt >= MIN_KEPT): threshold is exactly
// 0.7, speculative sums are the answer. Slow path (never taken for this
// input, kept for correctness): exact 3-level radix select over recomputed
// mask_prob bit patterns, then masked mean.
// ---------------------------------------------------------------------------
__global__ __launch_bounds__(256) void k_final(const float2* __restrict__ part,
                                               const float* __restrict__ pred,
                                               const int* __restrict__ target,
                                               float* __restrict__ out) {
    int tid = threadIdx.x;
    __shared__ double rs[256], rc[256];
    double s = 0.0, c = 0.0;
    for (int i = tid; i < NBLK; i += 256) {
        float2 p = part[i];
        s += (double)p.x; c += (double)p.y;
    }
    rs[tid] = s; rc[tid] = c;
    __syncthreads();
    for (int off = 128; off > 0; off >>= 1) {
        if (tid < off) { rs[tid] += rs[tid + off]; rc[tid] += rc[tid + off]; }
        __syncthreads();
    }
    double tots = rs[0], totc = rc[0];        // uniform across block after sync

    if (totc >= (double)MIN_KEPT) {
        if (tid == 0) out[0] = (float)(tots / (totc < 1.0 ? 1.0 : totc));
        return;                                // uniform exit
    }

    // ---- slow exact path ----
    __shared__ unsigned h[4096];
    __shared__ unsigned s_bin, s_krem;
    float dummy;

    // level 0: bits >> 20
    for (int i = tid; i < 4096; i += 256) h[i] = 0;
    __syncthreads();
    for (int nn = tid; nn < N_PIX; nn += 256) {
        unsigned bits = __float_as_uint(slow_prob(pred, target, nn, &dummy));
        atomicAdd(&h[bits >> 20], 1u);
    }
    __syncthreads();
    if (tid == 0) {
        unsigned run = 0;
        for (unsigned bb = 0; bb < 4096; ++bb) {
            unsigned cv = h[bb];
            if (MIN_KEPT <= run + cv) { s_bin = bb; s_krem = MIN_KEPT - run; break; }
            run += cv;
        }
    }
    __syncthreads();
    unsigned p0 = s_bin, k1 = s_krem;
    __syncthreads();

    // level 1: (bits >> 8) & 0xFFF
    for (int i = tid; i < 4096; i += 256) h[i] = 0;
    __syncthreads();
    for (int nn = tid; nn < N_PIX; nn += 256) {
        unsigned bits = __float_as_uint(slow_prob(pred, target, nn, &dummy));
        if ((bits >> 20) == p0) atomicAdd(&h[(bits >> 8) & 0xFFFu], 1u);
    }
    __syncthreads();
    if (tid == 0) {
        unsigned run = 0;
        for (unsigned bb = 0; bb < 4096; ++bb) {
            unsigned cv = h[bb];
            if (k1 <= run + cv) { s_bin = bb; s_krem = k1 - run; break; }
            run += cv;
        }
    }
    __syncthreads();
    unsigned p1 = (p0 << 12) | s_bin;
    unsigned k2 = s_krem;
    __syncthreads();

    // level 2: bits & 0xFF
    for (int i = tid; i < 256; i += 256) h[i] = 0;
    __syncthreads();
    for (int nn = tid; nn < N_PIX; nn += 256) {
        unsigned bits = __float_as_uint(slow_prob(pred, target, nn, &dummy));
        if ((bits >> 8) == p1) atomicAdd(&h[bits & 0xFFu], 1u);
    }
    __syncthreads();
    if (tid == 0) {
        unsigned run = 0;
        for (unsigned bb = 0; bb < 256; ++bb) {
            unsigned cv = h[bb];
            if (k2 <= run + cv) { s_bin = (p1 << 8) | bb; break; }
            run += cv;
        }
    }
    __syncthreads();
    float thr = fmaxf(THRESH, __uint_as_float(s_bin));

    // masked mean at exact threshold
    double fs = 0.0, fc = 0.0;
    for (int nn = tid; nn < N_PIX; nn += 256) {
        float nll;
        float mp = slow_prob(pred, target, nn, &nll);
        if (target[nn] != IGNORE_LABEL && mp <= thr) { fs += (double)nll; fc += 1.0; }
    }
    __syncthreads();
    rs[tid] = fs; rc[tid] = fc;
    __syncthreads();
    for (int off = 128; off > 0; off >>= 1) {
        if (tid < off) { rs[tid] += rs[tid + off]; rc[tid] += rc[tid + off]; }
        __syncthreads();
    }
    if (tid == 0) {
        double cc = rc[0] < 1.0 ? 1.0 : rc[0];
        out[0] = (float)(rs[0] / cc);
    }
}

extern "C" void kernel_launch(void* const* d_in, const int* in_sizes, int n_in,
                              void* d_out, int out_size, void* d_ws, size_t ws_size,
                              hipStream_t stream) {
    const float* pred = (const float*)d_in[0];
    const int* target = (const int*)d_in[1];
    float* out = (float*)d_out;

    float2* part = (float2*)d_ws;              // NBLK float2, written before read

    k_fused<<<NBLK, 256, 0, stream>>>(pred, target, part);
    k_final<<<1, 256, 0, stream>>>(part, pred, target, out);
}